// Round 8
// baseline (159.670 us; speedup 1.0000x reference)
//
#include <hip/hip_runtime.h>
#include <hip/hip_bf16.h>

// B=64, I=64, O=64, G=4096, X=4, RHO=1
#define BB 64
#define II 64
#define OO 64
#define GG 4096
#define KP 64            // g per phase; LDS row = 64 shorts = 128 B
#define NCH 8            // g-chunks (split-K) -> grid 64 x 8 = 512 blocks
#define GC (GG / NCH)    // 512 g per block
#define NPH (GC / KP)    // 8 phases

typedef short bf16x8 __attribute__((ext_vector_type(8)));
typedef short bf16x4 __attribute__((ext_vector_type(4)));
typedef float f32x4  __attribute__((ext_vector_type(4)));

static __device__ __forceinline__ short f2bf(float f) {
    __hip_bfloat16 h = __float2bfloat16(f);
    return __builtin_bit_cast(short, h);
}

// Raw barrier with LDS-only drain: ds ops visible across the barrier, global
// prefetch loads deliberately stay in flight (counted vmcnt at consumer).
static __device__ __forceinline__ void lds_barrier() {
    asm volatile("s_waitcnt lgkmcnt(0)" ::: "memory");
    __builtin_amdgcn_s_barrier();
}

// ---------------------------------------------------------------------------
// Main: bf16 MFMA split-K GEMM, software-pipelined.
//   C[b][(o,x)] += sum_g rbf[b,g] * w[o,g,x]   per block (i, ch) over 512 g.
//
// r8 change: KP 32 -> 64. DRAM-extent theory: r4-r7 all read each o-row in
// 512-B visits at 64-KB stride (page-locality collapse -> ~3.7 TB/s, and
// invariant to all issue-schedule changes, matching 3 nulls). KP=64 doubles
// the per-row extent to 1 KB, read by ONE wave-instruction (row = q*8+wv,
// col = lane -> 1 KB contiguous). 8 phases; 2 MFMA k-steps/phase.
// LDS: Bs 2x32 KB + As 2x8 KB = 80 KB -> 2 blocks/CU. One lds_barrier per
// phase (stage p+1 writes buf^1 while MFMA p reads buf; cross-phase safety
// by barrier ordering as before).
//
// Swizzle (128-B rows): element (row, k) lives at col k ^ ((row&7)<<3).
//   b16 writes: col = lane ^ const -> lane-consecutive, 2/bank = free.
//   b128 reads: uniform 8 accesses/bank = wave64-b128 minimum.
// ---------------------------------------------------------------------------
__global__ __launch_bounds__(512, 4)
void kan_main(const float* __restrict__ xg, const float* __restrict__ grd,
              const float* __restrict__ wts, float* __restrict__ dst,
              int atomic_mode)
{
    __shared__ __align__(16) unsigned short Bs[2][256 * KP];  // [n][k] 32KB x2
    __shared__ __align__(16) unsigned short As[2][BB * KP];   // [m][k]  8KB x2

    const int i  = blockIdx.x;
    const int ch = blockIdx.y;
    const int g0 = ch * GC;          // float4 index (1 float4 per g)

    const int t    = threadIdx.x;
    const int lane = t & 63;
    const int wv   = t >> 6;         // wave id 0..7

    // weight staging: load q covers row_o = q*8 + wv, col = lane
    //   -> one wave-instruction = 64 lanes x 16 B = 1 KB contiguous.
    const float4* wrow = reinterpret_cast<const float4*>(wts)
                         + (size_t)i * OO * GG + g0 + lane;

    // rbf task map: thread computes 8 g (two halves of 4) for one b
    const int brow = t >> 3;         // b-row
    const int oct  = t & 7;          // g-octet within phase
    const float4* gp = reinterpret_cast<const float4*>(grd) + g0 + oct * 8;
    const float4  xv = reinterpret_cast<const float4*>(xg)[brow * II + i];

    const int lg  = lane >> 4;       // k-octet selector within 32-k step
    const int r16 = lane & 15;

    f32x4 acc[4][2];
    #pragma unroll
    for (int mt = 0; mt < 4; ++mt)
        #pragma unroll
        for (int nt = 0; nt < 2; ++nt) acc[mt][nt] = {0.f, 0.f, 0.f, 0.f};

    // prologue: phase-0 weights (8 x 1-KB extents per wave)
    float4 pre[8];
    #pragma unroll
    for (int q = 0; q < 8; ++q)
        pre[q] = wrow[(size_t)(q * 8 + wv) * GG];

    for (int p = 0; p < NPH; ++p) {
        unsigned short* Bb = Bs[p & 1];
        unsigned short* Ab = As[p & 1];

        // ---- convert weights + swizzled LDS write; reissue load q ASAP ----
        #pragma unroll
        for (int q = 0; q < 8; ++q) {
            const int   row = q * 8 + wv;
            const float4 w4 = pre[q];                 // counted-vmcnt wait
            if (p + 1 < NPH)
                pre[q] = wrow[(size_t)row * GG + (p + 1) * KP];
            const float wf[4] = {w4.x, w4.y, w4.z, w4.w};
            #pragma unroll
            for (int x = 0; x < 4; ++x) {
                const int n = row * 4 + x;
                Bb[n * KP + (lane ^ ((n & 7) << 3))] =
                    (unsigned short)f2bf(wf[x]);
            }
        }

        // ---- rbf -> bf16, two 4-wide halves (keeps VGPR low) ----
        #pragma unroll
        for (int h = 0; h < 2; ++h) {
            float4 gv[4];
            #pragma unroll
            for (int e = 0; e < 4; ++e) gv[e] = gp[p * KP + h * 4 + e];
            bf16x4 av;
            #pragma unroll
            for (int e = 0; e < 4; ++e) {
                const float d0 = xv.x - gv[e].x, d1 = xv.y - gv[e].y,
                            d2 = xv.z - gv[e].z, d3 = xv.w - gv[e].w;
                av[e] = f2bf(__expf(-(d0*d0 + d1*d1 + d2*d2 + d3*d3)));
            }
            const int kb = oct * 8 + h * 4;
            *reinterpret_cast<bf16x4*>(
                &Ab[brow * KP + (kb ^ ((brow & 7) << 3))]) = av;
        }

        lds_barrier();   // buf[p&1] ready; global prefetch NOT drained

        // ---- MFMA: 2 k-steps x (4m x 2n) ----
        #pragma unroll
        for (int kk = 0; kk < 2; ++kk) {
            const int kb = kk * 32 + lg * 8;
            bf16x8 af[4], bb[2];
            #pragma unroll
            for (int mt = 0; mt < 4; ++mt) {
                const int r = mt * 16 + r16;
                af[mt] = *reinterpret_cast<const bf16x8*>(
                    &Ab[r * KP + (kb ^ ((r & 7) << 3))]);
            }
            #pragma unroll
            for (int nt = 0; nt < 2; ++nt) {
                const int r = wv * 32 + nt * 16 + r16;
                bb[nt] = *reinterpret_cast<const bf16x8*>(
                    &Bb[r * KP + (kb ^ ((r & 7) << 3))]);
            }
            #pragma unroll
            for (int mt = 0; mt < 4; ++mt)
                #pragma unroll
                for (int nt = 0; nt < 2; ++nt)
                    acc[mt][nt] = __builtin_amdgcn_mfma_f32_16x16x32_bf16(
                        af[mt], bb[nt], acc[mt][nt], 0, 0, 0);
        }
        // no second barrier: next phase writes buf^1, whose last reader
        // (MFMA p-1) is already behind this phase's barrier.
    }

    // ---- epilogue: C/D layout col=lane&15, row=(lane>>4)*4+reg ----
    if (!atomic_mode) {
        float* pp = dst + (size_t)(ch * 64 + i) * (BB * OO * 4);
        #pragma unroll
        for (int mt = 0; mt < 4; ++mt)
            #pragma unroll
            for (int nt = 0; nt < 2; ++nt) {
                const int n  = wv * 32 + nt * 16 + (lane & 15);
                const int mb = mt * 16 + ((lane >> 4) << 2);
                #pragma unroll
                for (int r = 0; r < 4; ++r)
                    pp[(mb + r) * 256 + n] = acc[mt][nt][r];
            }
    } else {
        #pragma unroll
        for (int mt = 0; mt < 4; ++mt)
            #pragma unroll
            for (int nt = 0; nt < 2; ++nt) {
                const int n  = wv * 32 + nt * 16 + (lane & 15);
                const int mb = mt * 16 + ((lane >> 4) << 2);
                #pragma unroll
                for (int r = 0; r < 4; ++r)
                    atomicAdd(&dst[(mb + r) * 256 + n], acc[mt][nt][r]);
            }
    }
}

// ---------------------------------------------------------------------------
// Tree-reduce 512 partials -> 4 slices
// ---------------------------------------------------------------------------
__global__ void kan_reduce(const float* __restrict__ part,
                           float* __restrict__ part2, int Q)
{
    const int idx = blockIdx.x * 256 + threadIdx.x;  // [0, 16384)
    const int pg  = blockIdx.y;                      // [0, 4)
    const float* p = part + (size_t)pg * Q * 16384 + idx;
    float s = 0.f;
    #pragma unroll 8
    for (int q = 0; q < Q; ++q) s += p[(size_t)q * 16384];
    part2[pg * 16384 + idx] = s;
}

// ---------------------------------------------------------------------------
// Final sum + SiLU/Cayley (Cl(2,0), static signs) + bias
// ---------------------------------------------------------------------------
__global__ void kan_out(const float* __restrict__ part2,
                        const float* __restrict__ xg,
                        const float* __restrict__ sw,
                        const float* __restrict__ sb,
                        float* __restrict__ out, int R)
{
    const int t = blockIdx.x * 256 + threadIdx.x;    // (b,o)
    const int b = t >> 6, o = t & 63;

    float o0, o1, o2, o3;
    if (R > 0) {
        o0 = o1 = o2 = o3 = 0.f;
        const float4* p2 = reinterpret_cast<const float4*>(part2);
        for (int r = 0; r < R; ++r) {
            const float4 v = p2[(size_t)r * 4096 + t];
            o0 += v.x; o1 += v.y; o2 += v.z; o3 += v.w;
        }
    } else {
        const float4 v = reinterpret_cast<const float4*>(out)[t];
        o0 = v.x; o1 = v.y; o2 = v.z; o3 = v.w;
    }

    const float4* xg4 = reinterpret_cast<const float4*>(xg);
    const float4* sw4 = reinterpret_cast<const float4*>(sw);
    const float4* sb4 = reinterpret_cast<const float4*>(sb);
    #pragma unroll 4
    for (int i = 0; i < II; ++i) {
        const float4 xvv = xg4[b * II + i];
        const float4 swv = sw4[i * OO + o];
        const float4 sbv = sb4[i * OO + o];
        const float s0 = xvv.x / (1.f + __expf(-xvv.x));
        const float s1 = xvv.y / (1.f + __expf(-xvv.y));
        const float s2 = xvv.z / (1.f + __expf(-xvv.z));
        const float s3 = xvv.w / (1.f + __expf(-xvv.w));
        o0 += swv.x * s0 + swv.y * s1 + swv.z * s2 - swv.w * s3 + sbv.x;
        o1 += swv.x * s1 + swv.y * s0 - swv.z * s3 + swv.w * s2 + sbv.y;
        o2 += swv.x * s2 + swv.y * s3 + swv.z * s0 - swv.w * s1 + sbv.z;
        o3 += swv.x * s3 + swv.y * s2 - swv.z * s1 + swv.w * s0 + sbv.w;
    }
    reinterpret_cast<float4*>(out)[t] = make_float4(o0, o1, o2, o3);
}

// ---------------------------------------------------------------------------
extern "C" void kernel_launch(void* const* d_in, const int* in_sizes, int n_in,
                              void* d_out, int out_size, void* d_ws, size_t ws_size,
                              hipStream_t stream)
{
    const float* x   = (const float*)d_in[0];
    const float* grd = (const float*)d_in[1];
    const float* w   = (const float*)d_in[2];
    const float* sw  = (const float*)d_in[3];
    const float* sb  = (const float*)d_in[4];
    float* out = (float*)d_out;
    float* ws  = (float*)d_ws;

    const size_t need = ((size_t)64 * NCH + 4) * 16384 * 4;  // 512 partials + 4 slices

    if (ws_size >= need) {
        float* part2 = ws + (size_t)64 * NCH * 16384;
        kan_main<<<dim3(64, NCH), 512, 0, stream>>>(x, grd, w, ws, 0);
        kan_reduce<<<dim3(64, 4), 256, 0, stream>>>(ws, part2, 64 * NCH / 4);
        kan_out<<<16, 256, 0, stream>>>(part2, x, sw, sb, out, 4);
    } else {
        hipMemsetAsync(d_out, 0, (size_t)out_size * sizeof(float), stream);
        kan_main<<<dim3(64, NCH), 512, 0, stream>>>(x, grd, w, out, 1);
        kan_out<<<16, 256, 0, stream>>>(nullptr, x, sw, sb, out, 0);
    }
}

// Round 9
// 86.910 us; speedup vs baseline: 1.8372x; 1.8372x over previous
//
#include <hip/hip_runtime.h>
#include <hip/hip_bf16.h>

// B=64, I=64, O=64, G=4096, X=4, RHO=1
#define BB 64
#define II 64
#define OO 64
#define GG 4096
#define KP 32            // g per phase
#define NCH 8            // split-K chunks -> grid 64 x 8 = 512 blocks
#define GC (GG / NCH)    // 512 g per block
#define NPH (GC / KP)    // 16 phases

typedef short bf16x8 __attribute__((ext_vector_type(8)));
typedef short bf16x4 __attribute__((ext_vector_type(4)));
typedef float f32x4  __attribute__((ext_vector_type(4)));

static __device__ __forceinline__ short f2bf(float f) {
    __hip_bfloat16 h = __float2bfloat16(f);
    return __builtin_bit_cast(short, h);
}

// ---------------------------------------------------------------------------
// r9: async-staging rewrite. r8's counters (VGPR=64, all pipes <10%) proved
// the compiler sinks register prefetches -> every phase serialized on HBM
// latency. Weights now stream HBM->LDS via global_load_lds (no dest regs,
// nothing to sink) as RAW f32, double-buffered, with counted s_waitcnt
// vmcnt(4) (never 0 mid-loop) so next-phase loads stay in flight across
// barriers (T3/T4, m201 pattern). f32->bf16 conversion moved to the consume
// side. Source-XOR swizzle (unit ^= row&7) at issue + same XOR on read
// (rule #21 both-sides) spreads consume-read banks (<=4-way b32).
//
// LDS: Wst 2x32KB (f32 [64 o-rows][32 units][4 x]) + As 2x4KB (bf16 rbf,
// r6 swizzle) + Gs 8KB (grid slice, staged once) = 80KB -> 2 blocks/CU.
//
// Phase p (b=p&1):  issue W(p+1)->Wst[b^1] (4 gload_lds)
//                   rbf(p)->As[b]
//                   s_waitcnt vmcnt(4) lgkmcnt(0); s_barrier   // W(p) ready
//                   consume: A-frags (b128), B-frags (8x ds_read_b32 + cvt),
//                            8 MFMA
//                   s_waitcnt lgkmcnt(0); s_barrier            // reads done
// Overwrite safety: Wst[b^1] was consumed in phase p-1 whose reads drained
// at p-1's end barrier; As[b] last read at p-2. vmcnt counting: steady state
// has exactly 8 outstanding (W(p),W(p+1)); vmcnt(4) retires W(p) only.
// ---------------------------------------------------------------------------
__global__ __launch_bounds__(512, 4)
void kan_main(const float* __restrict__ xg, const float* __restrict__ grd,
              const float* __restrict__ wts, float* __restrict__ dst,
              int atomic_mode)
{
    __shared__ __align__(16) float          Wst[2][OO * KP * 4]; // 32KB x2
    __shared__ __align__(16) unsigned short As [2][BB * KP];     //  4KB x2
    __shared__ __align__(16) float4         Gs [GC];             //  8KB

    const int i  = blockIdx.x;
    const int ch = blockIdx.y;
    const int g0 = ch * GC;          // in float4 units (1 float4 per g)

    const int t    = threadIdx.x;
    const int lane = t & 63;
    const int wv   = t >> 6;

    // rbf map: thread computes 4 g for one b-row
    const int brow = t >> 3;
    const int gq   = t & 7;
    const float4 xv = reinterpret_cast<const float4*>(xg)[brow * II + i];

    // ---- prologue: grid slice -> LDS (1 x 16B per thread) ----
    {
        const float4* gsrc = reinterpret_cast<const float4*>(grd) + g0 + t;
        char* ldst = (char*)(&Gs[0]) + wv * 1024;   // uniform per wave
        __builtin_amdgcn_global_load_lds(gsrc, ldst, 16, 0, 0);
    }

    // weight staging: inst q covers row-pair 2*(q*8+wv); lane supplies
    // row = +lane>>5, unit u = lane&31, fetched source unit u^(row&7).
    const float4* w4 = reinterpret_cast<const float4*>(wts)
                       + (size_t)i * OO * GG;
    const int srow_half = lane >> 5;
    const int su        = lane & 31;

    #pragma unroll
    for (int q = 0; q < 4; ++q) {                  // W(0) -> Wst[0]
        const int rr = 2 * (q * 8 + wv) + srow_half;
        const int gg = g0 + (su ^ (rr & 7));
        __builtin_amdgcn_global_load_lds(w4 + (size_t)rr * GG + gg,
            (char*)(&Wst[0][0]) + (q * 8 + wv) * 1024, 16, 0, 0);
    }

    // grid (and xv) landed; W(0)'s 4 stay in flight
    asm volatile("s_waitcnt vmcnt(4)\n\ts_barrier" ::: "memory");

    f32x4 acc[4][2];
    #pragma unroll
    for (int mt = 0; mt < 4; ++mt)
        #pragma unroll
        for (int nt = 0; nt < 2; ++nt) acc[mt][nt] = {0.f, 0.f, 0.f, 0.f};

    const int lg    = lane >> 4;     // k-octet selector
    const int r16   = lane & 15;
    const int bo_lo = r16 >> 2;      // o offset within an nt quad
    const int bx    = r16 & 3;       // x component

    for (int p = 0; p < NPH; ++p) {
        const int b = p & 1;

        // ---- issue W(p+1) -> Wst[b^1] (async, rides across barriers) ----
        if (p + 1 < NPH) {
            #pragma unroll
            for (int q = 0; q < 4; ++q) {
                const int rr = 2 * (q * 8 + wv) + srow_half;
                const int gg = g0 + (p + 1) * KP + (su ^ (rr & 7));
                __builtin_amdgcn_global_load_lds(w4 + (size_t)rr * GG + gg,
                    (char*)(&Wst[b ^ 1][0]) + (q * 8 + wv) * 1024, 16, 0, 0);
            }
        }

        // ---- rbf(p) -> As[b] (grid from LDS: lgkm only) ----
        {
            bf16x4 av;
            #pragma unroll
            for (int e = 0; e < 4; ++e) {
                const float4 gv = Gs[p * KP + gq * 4 + e];
                const float d0 = xv.x - gv.x, d1 = xv.y - gv.y,
                            d2 = xv.z - gv.z, d3 = xv.w - gv.w;
                av[e] = f2bf(__expf(-(d0*d0 + d1*d1 + d2*d2 + d3*d3)));
            }
            *reinterpret_cast<bf16x4*>(
                &As[b][brow * KP + ((gq * 4) ^ ((brow & 3) << 3))]) = av;
        }

        // ---- mid barrier: W(p) landed (counted!), As[b] visible ----
        if (p + 1 < NPH)
            asm volatile("s_waitcnt vmcnt(4) lgkmcnt(0)\n\ts_barrier" ::: "memory");
        else
            asm volatile("s_waitcnt vmcnt(0) lgkmcnt(0)\n\ts_barrier" ::: "memory");

        // ---- consume: fragments + MFMA ----
        bf16x8 af[4];
        #pragma unroll
        for (int mt = 0; mt < 4; ++mt) {
            const int r = mt * 16 + r16;
            af[mt] = *reinterpret_cast<const bf16x8*>(
                &As[b][r * KP + ((lg * 8) ^ ((r & 3) << 3))]);
        }
        bf16x8 bb[2];
        #pragma unroll
        for (int nt = 0; nt < 2; ++nt) {
            const int o  = wv * 8 + nt * 4 + bo_lo;
            const int sg = o & 7;
            const float* bp = &Wst[b][o * 128 + bx];
            #pragma unroll
            for (int e = 0; e < 8; ++e)
                bb[nt][e] = f2bf(bp[(lg * 8 + (e ^ sg)) * 4]);
        }
        #pragma unroll
        for (int mt = 0; mt < 4; ++mt)
            #pragma unroll
            for (int nt = 0; nt < 2; ++nt)
                acc[mt][nt] = __builtin_amdgcn_mfma_f32_16x16x32_bf16(
                    af[mt], bb[nt], acc[mt][nt], 0, 0, 0);

        // ---- end barrier: this wave's LDS reads retired -> next phase may
        //      overwrite Wst[b^1]/As[b^1] ----
        asm volatile("s_waitcnt lgkmcnt(0)\n\ts_barrier" ::: "memory");
    }

    // ---- epilogue: C/D layout col=lane&15, row=(lane>>4)*4+reg ----
    if (!atomic_mode) {
        float* pp = dst + (size_t)(ch * 64 + i) * (BB * OO * 4);
        #pragma unroll
        for (int mt = 0; mt < 4; ++mt)
            #pragma unroll
            for (int nt = 0; nt < 2; ++nt) {
                const int n  = wv * 32 + nt * 16 + (lane & 15);
                const int mb = mt * 16 + ((lane >> 4) << 2);
                #pragma unroll
                for (int r = 0; r < 4; ++r)
                    pp[(mb + r) * 256 + n] = acc[mt][nt][r];
            }
    } else {
        #pragma unroll
        for (int mt = 0; mt < 4; ++mt)
            #pragma unroll
            for (int nt = 0; nt < 2; ++nt) {
                const int n  = wv * 32 + nt * 16 + (lane & 15);
                const int mb = mt * 16 + ((lane >> 4) << 2);
                #pragma unroll
                for (int r = 0; r < 4; ++r)
                    atomicAdd(&dst[(mb + r) * 256 + n], acc[mt][nt][r]);
            }
    }
}

// ---------------------------------------------------------------------------
// Tree-reduce 512 partials -> 4 slices
// ---------------------------------------------------------------------------
__global__ void kan_reduce(const float* __restrict__ part,
                           float* __restrict__ part2, int Q)
{
    const int idx = blockIdx.x * 256 + threadIdx.x;  // [0, 16384)
    const int pg  = blockIdx.y;                      // [0, 4)
    const float* p = part + (size_t)pg * Q * 16384 + idx;
    float s = 0.f;
    #pragma unroll 8
    for (int q = 0; q < Q; ++q) s += p[(size_t)q * 16384];
    part2[pg * 16384 + idx] = s;
}

// ---------------------------------------------------------------------------
// Final sum + SiLU/Cayley (Cl(2,0), static signs) + bias
// ---------------------------------------------------------------------------
__global__ void kan_out(const float* __restrict__ part2,
                        const float* __restrict__ xg,
                        const float* __restrict__ sw,
                        const float* __restrict__ sb,
                        float* __restrict__ out, int R)
{
    const int t = blockIdx.x * 256 + threadIdx.x;    // (b,o)
    const int b = t >> 6, o = t & 63;

    float o0, o1, o2, o3;
    if (R > 0) {
        o0 = o1 = o2 = o3 = 0.f;
        const float4* p2 = reinterpret_cast<const float4*>(part2);
        for (int r = 0; r < R; ++r) {
            const float4 v = p2[(size_t)r * 4096 + t];
            o0 += v.x; o1 += v.y; o2 += v.z; o3 += v.w;
        }
    } else {
        const float4 v = reinterpret_cast<const float4*>(out)[t];
        o0 = v.x; o1 = v.y; o2 = v.z; o3 = v.w;
    }

    const float4* xg4 = reinterpret_cast<const float4*>(xg);
    const float4* sw4 = reinterpret_cast<const float4*>(sw);
    const float4* sb4 = reinterpret_cast<const float4*>(sb);
    #pragma unroll 4
    for (int i = 0; i < II; ++i) {
        const float4 xvv = xg4[b * II + i];
        const float4 swv = sw4[i * OO + o];
        const float4 sbv = sb4[i * OO + o];
        const float s0 = xvv.x / (1.f + __expf(-xvv.x));
        const float s1 = xvv.y / (1.f + __expf(-xvv.y));
        const float s2 = xvv.z / (1.f + __expf(-xvv.z));
        const float s3 = xvv.w / (1.f + __expf(-xvv.w));
        o0 += swv.x * s0 + swv.y * s1 + swv.z * s2 - swv.w * s3 + sbv.x;
        o1 += swv.x * s1 + swv.y * s0 - swv.z * s3 + swv.w * s2 + sbv.y;
        o2 += swv.x * s2 + swv.y * s3 + swv.z * s0 - swv.w * s1 + sbv.z;
        o3 += swv.x * s3 + swv.y * s2 - swv.z * s1 + swv.w * s0 + sbv.w;
    }
    reinterpret_cast<float4*>(out)[t] = make_float4(o0, o1, o2, o3);
}

// ---------------------------------------------------------------------------
extern "C" void kernel_launch(void* const* d_in, const int* in_sizes, int n_in,
                              void* d_out, int out_size, void* d_ws, size_t ws_size,
                              hipStream_t stream)
{
    const float* x   = (const float*)d_in[0];
    const float* grd = (const float*)d_in[1];
    const float* w   = (const float*)d_in[2];
    const float* sw  = (const float*)d_in[3];
    const float* sb  = (const float*)d_in[4];
    float* out = (float*)d_out;
    float* ws  = (float*)d_ws;

    const size_t need = ((size_t)64 * NCH + 4) * 16384 * 4;  // 512 partials + 4 slices

    if (ws_size >= need) {
        float* part2 = ws + (size_t)64 * NCH * 16384;
        kan_main<<<dim3(64, NCH), 512, 0, stream>>>(x, grd, w, ws, 0);
        kan_reduce<<<dim3(64, 4), 256, 0, stream>>>(ws, part2, 64 * NCH / 4);
        kan_out<<<16, 256, 0, stream>>>(part2, x, sw, sb, out, 4);
    } else {
        hipMemsetAsync(d_out, 0, (size_t)out_size * sizeof(float), stream);
        kan_main<<<dim3(64, NCH), 512, 0, stream>>>(x, grd, w, out, 1);
        kan_out<<<16, 256, 0, stream>>>(nullptr, x, sw, sb, out, 0);
    }
}

// Round 10
// 79.880 us; speedup vs baseline: 1.9989x; 1.0880x over previous
//
#include <hip/hip_runtime.h>
#include <hip/hip_bf16.h>

// B=64, I=64, O=64, G=4096, X=4, RHO=1
#define BB 64
#define II 64
#define OO 64
#define GG 4096
#define KP 32            // g per phase
#define NCH 8            // split-K chunks -> grid 64 x 8 = 512 blocks
#define GC (GG / NCH)    // 512 g per block
#define NPH (GC / KP)    // 16 phases

typedef short bf16x8 __attribute__((ext_vector_type(8)));
typedef short bf16x4 __attribute__((ext_vector_type(4)));
typedef float f32x4  __attribute__((ext_vector_type(4)));

static __device__ __forceinline__ short f2bf(float f) {
    __hip_bfloat16 h = __float2bfloat16(f);
    return __builtin_bit_cast(short, h);
}

// ---------------------------------------------------------------------------
// r10: PER-BLOCK PHASE ROTATION on top of the r9 async-staging structure.
// Channel-decorrelation theory: all blocks march in lockstep through phase
// p, so concurrent weight addresses are i*4MB + o*64KB + ch*8KB + p*512B --
// address bits 9-12 are FROZEN device-wide at any instant (set by p alone),
// starving the HBM channel interleave. That property is invariant to issue
// scheduling, which is why r5(sync)/r6(coalesce)/r7(depth-2)/r9(gload_lds+
// counted vmcnt) were all nulls at ~72 us (3.7 TB/s). Rotating each block's
// phase order by s = (i+ch)&15 (g-sum is commutative) makes bits 9-12 take
// all 16 values across co-resident blocks at every instant.
//
// Structure (r9): weights HBM->LDS raw f32 via global_load_lds (no dest
// regs), double-buffered, counted s_waitcnt vmcnt(4) mid-loop (never 0);
// f32->bf16 on consume side; source-XOR swizzle (unit ^= row&7) at issue +
// same XOR on read. LDS: Wst 2x32KB + As 2x4KB + Gs 8KB = 80KB, 2 blk/CU.
// ---------------------------------------------------------------------------
__global__ __launch_bounds__(512, 4)
void kan_main(const float* __restrict__ xg, const float* __restrict__ grd,
              const float* __restrict__ wts, float* __restrict__ dst,
              int atomic_mode)
{
    __shared__ __align__(16) float          Wst[2][OO * KP * 4]; // 32KB x2
    __shared__ __align__(16) unsigned short As [2][BB * KP];     //  4KB x2
    __shared__ __align__(16) float4         Gs [GC];             //  8KB

    const int i  = blockIdx.x;
    const int ch = blockIdx.y;
    const int g0 = ch * GC;          // in float4 units (1 float4 per g)
    const int s  = (i + ch) & (NPH - 1);   // phase rotation offset

    const int t    = threadIdx.x;
    const int lane = t & 63;
    const int wv   = t >> 6;

    // rbf map: thread computes 4 g for one b-row
    const int brow = t >> 3;
    const int gq   = t & 7;
    const float4 xv = reinterpret_cast<const float4*>(xg)[brow * II + i];

    // ---- prologue: grid slice -> LDS (1 x 16B per thread) ----
    {
        const float4* gsrc = reinterpret_cast<const float4*>(grd) + g0 + t;
        char* ldst = (char*)(&Gs[0]) + wv * 1024;   // uniform per wave
        __builtin_amdgcn_global_load_lds(gsrc, ldst, 16, 0, 0);
    }

    // weight staging: inst q covers row-pair 2*(q*8+wv); lane supplies
    // row = +lane>>5, unit u = lane&31, fetched source unit u^(row&7).
    const float4* w4 = reinterpret_cast<const float4*>(wts)
                       + (size_t)i * OO * GG;
    const int srow_half = lane >> 5;
    const int su        = lane & 31;

    #pragma unroll
    for (int q = 0; q < 4; ++q) {                  // W(phase s) -> Wst[0]
        const int rr = 2 * (q * 8 + wv) + srow_half;
        const int gg = g0 + s * KP + (su ^ (rr & 7));
        __builtin_amdgcn_global_load_lds(w4 + (size_t)rr * GG + gg,
            (char*)(&Wst[0][0]) + (q * 8 + wv) * 1024, 16, 0, 0);
    }

    // grid (and xv) landed; W(s)'s 4 stay in flight
    asm volatile("s_waitcnt vmcnt(4)\n\ts_barrier" ::: "memory");

    f32x4 acc[4][2];
    #pragma unroll
    for (int mt = 0; mt < 4; ++mt)
        #pragma unroll
        for (int nt = 0; nt < 2; ++nt) acc[mt][nt] = {0.f, 0.f, 0.f, 0.f};

    const int lg    = lane >> 4;     // k-octet selector
    const int r16   = lane & 15;
    const int bo_lo = r16 >> 2;      // o offset within an nt quad
    const int bx    = r16 & 3;       // x component

    for (int p = 0; p < NPH; ++p) {
        const int b  = p & 1;
        const int cp = (p + s) & (NPH - 1);        // phase being computed
        const int np = (p + 1 + s) & (NPH - 1);    // phase being issued

        // ---- issue W(np) -> Wst[b^1] (async, rides across barriers) ----
        if (p + 1 < NPH) {
            #pragma unroll
            for (int q = 0; q < 4; ++q) {
                const int rr = 2 * (q * 8 + wv) + srow_half;
                const int gg = g0 + np * KP + (su ^ (rr & 7));
                __builtin_amdgcn_global_load_lds(w4 + (size_t)rr * GG + gg,
                    (char*)(&Wst[b ^ 1][0]) + (q * 8 + wv) * 1024, 16, 0, 0);
            }
        }

        // ---- rbf(cp) -> As[b] (grid from LDS: lgkm only) ----
        {
            bf16x4 av;
            #pragma unroll
            for (int e = 0; e < 4; ++e) {
                const float4 gv = Gs[cp * KP + gq * 4 + e];
                const float d0 = xv.x - gv.x, d1 = xv.y - gv.y,
                            d2 = xv.z - gv.z, d3 = xv.w - gv.w;
                av[e] = f2bf(__expf(-(d0*d0 + d1*d1 + d2*d2 + d3*d3)));
            }
            *reinterpret_cast<bf16x4*>(
                &As[b][brow * KP + ((gq * 4) ^ ((brow & 3) << 3))]) = av;
        }

        // ---- mid barrier: W(cp) landed (counted!), As[b] visible ----
        if (p + 1 < NPH)
            asm volatile("s_waitcnt vmcnt(4) lgkmcnt(0)\n\ts_barrier" ::: "memory");
        else
            asm volatile("s_waitcnt vmcnt(0) lgkmcnt(0)\n\ts_barrier" ::: "memory");

        // ---- consume: fragments + MFMA ----
        bf16x8 af[4];
        #pragma unroll
        for (int mt = 0; mt < 4; ++mt) {
            const int r = mt * 16 + r16;
            af[mt] = *reinterpret_cast<const bf16x8*>(
                &As[b][r * KP + ((lg * 8) ^ ((r & 3) << 3))]);
        }
        bf16x8 bb[2];
        #pragma unroll
        for (int nt = 0; nt < 2; ++nt) {
            const int o  = wv * 8 + nt * 4 + bo_lo;
            const int sg = o & 7;
            const float* bp = &Wst[b][o * 128 + bx];
            #pragma unroll
            for (int e = 0; e < 8; ++e)
                bb[nt][e] = f2bf(bp[(lg * 8 + (e ^ sg)) * 4]);
        }
        #pragma unroll
        for (int mt = 0; mt < 4; ++mt)
            #pragma unroll
            for (int nt = 0; nt < 2; ++nt)
                acc[mt][nt] = __builtin_amdgcn_mfma_f32_16x16x32_bf16(
                    af[mt], bb[nt], acc[mt][nt], 0, 0, 0);

        // ---- end barrier: this wave's LDS reads retired -> next phase may
        //      overwrite Wst[b^1]/As[b^1] ----
        asm volatile("s_waitcnt lgkmcnt(0)\n\ts_barrier" ::: "memory");
    }

    // ---- epilogue: C/D layout col=lane&15, row=(lane>>4)*4+reg ----
    if (!atomic_mode) {
        float* pp = dst + (size_t)(ch * 64 + i) * (BB * OO * 4);
        #pragma unroll
        for (int mt = 0; mt < 4; ++mt)
            #pragma unroll
            for (int nt = 0; nt < 2; ++nt) {
                const int n  = wv * 32 + nt * 16 + (lane & 15);
                const int mb = mt * 16 + ((lane >> 4) << 2);
                #pragma unroll
                for (int r = 0; r < 4; ++r)
                    pp[(mb + r) * 256 + n] = acc[mt][nt][r];
            }
    } else {
        #pragma unroll
        for (int mt = 0; mt < 4; ++mt)
            #pragma unroll
            for (int nt = 0; nt < 2; ++nt) {
                const int n  = wv * 32 + nt * 16 + (lane & 15);
                const int mb = mt * 16 + ((lane >> 4) << 2);
                #pragma unroll
                for (int r = 0; r < 4; ++r)
                    atomicAdd(&dst[(mb + r) * 256 + n], acc[mt][nt][r]);
            }
    }
}

// ---------------------------------------------------------------------------
// Tree-reduce 512 partials -> 4 slices
// ---------------------------------------------------------------------------
__global__ void kan_reduce(const float* __restrict__ part,
                           float* __restrict__ part2, int Q)
{
    const int idx = blockIdx.x * 256 + threadIdx.x;  // [0, 16384)
    const int pg  = blockIdx.y;                      // [0, 4)
    const float* p = part + (size_t)pg * Q * 16384 + idx;
    float s = 0.f;
    #pragma unroll 8
    for (int q = 0; q < Q; ++q) s += p[(size_t)q * 16384];
    part2[pg * 16384 + idx] = s;
}

// ---------------------------------------------------------------------------
// Final sum + SiLU/Cayley (Cl(2,0), static signs) + bias
// ---------------------------------------------------------------------------
__global__ void kan_out(const float* __restrict__ part2,
                        const float* __restrict__ xg,
                        const float* __restrict__ sw,
                        const float* __restrict__ sb,
                        float* __restrict__ out, int R)
{
    const int t = blockIdx.x * 256 + threadIdx.x;    // (b,o)
    const int b = t >> 6, o = t & 63;

    float o0, o1, o2, o3;
    if (R > 0) {
        o0 = o1 = o2 = o3 = 0.f;
        const float4* p2 = reinterpret_cast<const float4*>(part2);
        for (int r = 0; r < R; ++r) {
            const float4 v = p2[(size_t)r * 4096 + t];
            o0 += v.x; o1 += v.y; o2 += v.z; o3 += v.w;
        }
    } else {
        const float4 v = reinterpret_cast<const float4*>(out)[t];
        o0 = v.x; o1 = v.y; o2 = v.z; o3 = v.w;
    }

    const float4* xg4 = reinterpret_cast<const float4*>(xg);
    const float4* sw4 = reinterpret_cast<const float4*>(sw);
    const float4* sb4 = reinterpret_cast<const float4*>(sb);
    #pragma unroll 4
    for (int i = 0; i < II; ++i) {
        const float4 xvv = xg4[b * II + i];
        const float4 swv = sw4[i * OO + o];
        const float4 sbv = sb4[i * OO + o];
        const float s0 = xvv.x / (1.f + __expf(-xvv.x));
        const float s1 = xvv.y / (1.f + __expf(-xvv.y));
        const float s2 = xvv.z / (1.f + __expf(-xvv.z));
        const float s3 = xvv.w / (1.f + __expf(-xvv.w));
        o0 += swv.x * s0 + swv.y * s1 + swv.z * s2 - swv.w * s3 + sbv.x;
        o1 += swv.x * s1 + swv.y * s0 - swv.z * s3 + swv.w * s2 + sbv.y;
        o2 += swv.x * s2 + swv.y * s3 + swv.z * s0 - swv.w * s1 + sbv.z;
        o3 += swv.x * s3 + swv.y * s2 - swv.z * s1 + swv.w * s0 + sbv.w;
    }
    reinterpret_cast<float4*>(out)[t] = make_float4(o0, o1, o2, o3);
}

// ---------------------------------------------------------------------------
extern "C" void kernel_launch(void* const* d_in, const int* in_sizes, int n_in,
                              void* d_out, int out_size, void* d_ws, size_t ws_size,
                              hipStream_t stream)
{
    const float* x   = (const float*)d_in[0];
    const float* grd = (const float*)d_in[1];
    const float* w   = (const float*)d_in[2];
    const float* sw  = (const float*)d_in[3];
    const float* sb  = (const float*)d_in[4];
    float* out = (float*)d_out;
    float* ws  = (float*)d_ws;

    const size_t need = ((size_t)64 * NCH + 4) * 16384 * 4;  // 512 partials + 4 slices

    if (ws_size >= need) {
        float* part2 = ws + (size_t)64 * NCH * 16384;
        kan_main<<<dim3(64, NCH), 512, 0, stream>>>(x, grd, w, ws, 0);
        kan_reduce<<<dim3(64, 4), 256, 0, stream>>>(ws, part2, 64 * NCH / 4);
        kan_out<<<16, 256, 0, stream>>>(part2, x, sw, sb, out, 4);
    } else {
        hipMemsetAsync(d_out, 0, (size_t)out_size * sizeof(float), stream);
        kan_main<<<dim3(64, NCH), 512, 0, stream>>>(x, grd, w, out, 1);
        kan_out<<<16, 256, 0, stream>>>(nullptr, x, sw, sb, out, 0);
    }
}

// Round 11
// 76.209 us; speedup vs baseline: 2.0952x; 1.0482x over previous
//
#include <hip/hip_runtime.h>
#include <hip/hip_bf16.h>

// B=64, I=64, O=64, G=4096, X=4, RHO=1
#define BB 64
#define II 64
#define OO 64
#define GG 4096
#define KP 32            // g per phase
#define NCH 8            // split-K chunks -> grid 64 x 8 = 512 blocks
#define GC (GG / NCH)    // 512 g per block
#define NPH (GC / KP)    // 16 phases

typedef short bf16x8 __attribute__((ext_vector_type(8)));
typedef short bf16x4 __attribute__((ext_vector_type(4)));
typedef float f32x4  __attribute__((ext_vector_type(4)));

static __device__ __forceinline__ short f2bf(float f) {
    __hip_bfloat16 h = __float2bfloat16(f);
    return __builtin_bit_cast(short, h);
}

// ---------------------------------------------------------------------------
// kan_main: UNCHANGED from r10 (passing, ~60-65 us).
// r9 async-staging structure (weights HBM->LDS raw f32 via global_load_lds,
// double-buffered, counted s_waitcnt vmcnt(4) mid-loop) + r10 per-block
// phase rotation s=(i+ch)&15 (decorrelates address bits 9-12 device-wide;
// +7 us, the only non-null of r5-r10's kan_main experiments).
// ---------------------------------------------------------------------------
__global__ __launch_bounds__(512, 4)
void kan_main(const float* __restrict__ xg, const float* __restrict__ grd,
              const float* __restrict__ wts, float* __restrict__ dst,
              int atomic_mode)
{
    __shared__ __align__(16) float          Wst[2][OO * KP * 4]; // 32KB x2
    __shared__ __align__(16) unsigned short As [2][BB * KP];     //  4KB x2
    __shared__ __align__(16) float4         Gs [GC];             //  8KB

    const int i  = blockIdx.x;
    const int ch = blockIdx.y;
    const int g0 = ch * GC;          // in float4 units (1 float4 per g)
    const int s  = (i + ch) & (NPH - 1);   // phase rotation offset

    const int t    = threadIdx.x;
    const int lane = t & 63;
    const int wv   = t >> 6;

    // rbf map: thread computes 4 g for one b-row
    const int brow = t >> 3;
    const int gq   = t & 7;
    const float4 xv = reinterpret_cast<const float4*>(xg)[brow * II + i];

    // ---- prologue: grid slice -> LDS (1 x 16B per thread) ----
    {
        const float4* gsrc = reinterpret_cast<const float4*>(grd) + g0 + t;
        char* ldst = (char*)(&Gs[0]) + wv * 1024;   // uniform per wave
        __builtin_amdgcn_global_load_lds(gsrc, ldst, 16, 0, 0);
    }

    // weight staging: inst q covers row-pair 2*(q*8+wv); lane supplies
    // row = +lane>>5, unit u = lane&31, fetched source unit u^(row&7).
    const float4* w4 = reinterpret_cast<const float4*>(wts)
                       + (size_t)i * OO * GG;
    const int srow_half = lane >> 5;
    const int su        = lane & 31;

    #pragma unroll
    for (int q = 0; q < 4; ++q) {                  // W(phase s) -> Wst[0]
        const int rr = 2 * (q * 8 + wv) + srow_half;
        const int gg = g0 + s * KP + (su ^ (rr & 7));
        __builtin_amdgcn_global_load_lds(w4 + (size_t)rr * GG + gg,
            (char*)(&Wst[0][0]) + (q * 8 + wv) * 1024, 16, 0, 0);
    }

    // grid (and xv) landed; W(s)'s 4 stay in flight
    asm volatile("s_waitcnt vmcnt(4)\n\ts_barrier" ::: "memory");

    f32x4 acc[4][2];
    #pragma unroll
    for (int mt = 0; mt < 4; ++mt)
        #pragma unroll
        for (int nt = 0; nt < 2; ++nt) acc[mt][nt] = {0.f, 0.f, 0.f, 0.f};

    const int lg    = lane >> 4;     // k-octet selector
    const int r16   = lane & 15;
    const int bo_lo = r16 >> 2;      // o offset within an nt quad
    const int bx    = r16 & 3;       // x component

    for (int p = 0; p < NPH; ++p) {
        const int b  = p & 1;
        const int cp = (p + s) & (NPH - 1);        // phase being computed
        const int np = (p + 1 + s) & (NPH - 1);    // phase being issued

        // ---- issue W(np) -> Wst[b^1] (async, rides across barriers) ----
        if (p + 1 < NPH) {
            #pragma unroll
            for (int q = 0; q < 4; ++q) {
                const int rr = 2 * (q * 8 + wv) + srow_half;
                const int gg = g0 + np * KP + (su ^ (rr & 7));
                __builtin_amdgcn_global_load_lds(w4 + (size_t)rr * GG + gg,
                    (char*)(&Wst[b ^ 1][0]) + (q * 8 + wv) * 1024, 16, 0, 0);
            }
        }

        // ---- rbf(cp) -> As[b] (grid from LDS: lgkm only) ----
        {
            bf16x4 av;
            #pragma unroll
            for (int e = 0; e < 4; ++e) {
                const float4 gv = Gs[cp * KP + gq * 4 + e];
                const float d0 = xv.x - gv.x, d1 = xv.y - gv.y,
                            d2 = xv.z - gv.z, d3 = xv.w - gv.w;
                av[e] = f2bf(__expf(-(d0*d0 + d1*d1 + d2*d2 + d3*d3)));
            }
            *reinterpret_cast<bf16x4*>(
                &As[b][brow * KP + ((gq * 4) ^ ((brow & 3) << 3))]) = av;
        }

        // ---- mid barrier: W(cp) landed (counted!), As[b] visible ----
        if (p + 1 < NPH)
            asm volatile("s_waitcnt vmcnt(4) lgkmcnt(0)\n\ts_barrier" ::: "memory");
        else
            asm volatile("s_waitcnt vmcnt(0) lgkmcnt(0)\n\ts_barrier" ::: "memory");

        // ---- consume: fragments + MFMA ----
        bf16x8 af[4];
        #pragma unroll
        for (int mt = 0; mt < 4; ++mt) {
            const int r = mt * 16 + r16;
            af[mt] = *reinterpret_cast<const bf16x8*>(
                &As[b][r * KP + ((lg * 8) ^ ((r & 3) << 3))]);
        }
        bf16x8 bb[2];
        #pragma unroll
        for (int nt = 0; nt < 2; ++nt) {
            const int o  = wv * 8 + nt * 4 + bo_lo;
            const int sg = o & 7;
            const float* bp = &Wst[b][o * 128 + bx];
            #pragma unroll
            for (int e = 0; e < 8; ++e)
                bb[nt][e] = f2bf(bp[(lg * 8 + (e ^ sg)) * 4]);
        }
        #pragma unroll
        for (int mt = 0; mt < 4; ++mt)
            #pragma unroll
            for (int nt = 0; nt < 2; ++nt)
                acc[mt][nt] = __builtin_amdgcn_mfma_f32_16x16x32_bf16(
                    af[mt], bb[nt], acc[mt][nt], 0, 0, 0);

        // ---- end barrier: this wave's LDS reads retired -> next phase may
        //      overwrite Wst[b^1]/As[b^1] ----
        asm volatile("s_waitcnt lgkmcnt(0)\n\ts_barrier" ::: "memory");
    }

    // ---- epilogue: C/D layout col=lane&15, row=(lane>>4)*4+reg ----
    if (!atomic_mode) {
        float* pp = dst + (size_t)(ch * 64 + i) * (BB * OO * 4);
        #pragma unroll
        for (int mt = 0; mt < 4; ++mt)
            #pragma unroll
            for (int nt = 0; nt < 2; ++nt) {
                const int n  = wv * 32 + nt * 16 + (lane & 15);
                const int mb = mt * 16 + ((lane >> 4) << 2);
                #pragma unroll
                for (int r = 0; r < 4; ++r)
                    pp[(mb + r) * 256 + n] = acc[mt][nt][r];
            }
    } else {
        #pragma unroll
        for (int mt = 0; mt < 4; ++mt)
            #pragma unroll
            for (int nt = 0; nt < 2; ++nt) {
                const int n  = wv * 32 + nt * 16 + (lane & 15);
                const int mb = mt * 16 + ((lane >> 4) << 2);
                #pragma unroll
                for (int r = 0; r < 4; ++r)
                    atomicAdd(&dst[(mb + r) * 256 + n], acc[mt][nt][r]);
            }
    }
}

// ---------------------------------------------------------------------------
// r11: FUSED TAIL. Replaces kan_reduce (256 blk) + kan_out (16 blk!) + one
// graph bubble with a single 256-block kernel:
//   phase 1: all 256 threads sum the 512 partials for the block's 16 (b,o)
//            pairs (thread = pair x 32-row group; fixed order -> det.)
//   phase 2: 16 threads do the 16-fold LDS reduce + the 64-i SiLU/Cayley
//            loop (L2-hot 64KB tables) and write the final float4.
// Partial slice r layout (from kan_main epilogue): [b][o*4+x] = [64][256]f32
// -> float4 index (r, b*64+o).
// ---------------------------------------------------------------------------
__global__ __launch_bounds__(256)
void kan_tail(const float* __restrict__ part,
              const float* __restrict__ xg,
              const float* __restrict__ sw,
              const float* __restrict__ sb,
              float* __restrict__ out)
{
    __shared__ float4 sums[16][16];          // [pairL][rgrp]

    const int t     = threadIdx.x;
    const int bid   = blockIdx.x;            // 0..255
    const int pairL = t & 15;
    const int rgrp  = t >> 4;
    const int pairG = bid * 16 + pairL;

    const float4* p4 = reinterpret_cast<const float4*>(part);
    float4 s = make_float4(0.f, 0.f, 0.f, 0.f);
    #pragma unroll 8
    for (int k = 0; k < 32; ++k) {
        const float4 v = p4[(size_t)(rgrp * 32 + k) * 4096 + pairG];
        s.x += v.x; s.y += v.y; s.z += v.z; s.w += v.w;
    }
    sums[pairL][rgrp] = s;
    __syncthreads();

    if (t < 16) {
        const int pg = bid * 16 + t;
        const int b = pg >> 6, o = pg & 63;

        float o0 = 0.f, o1 = 0.f, o2 = 0.f, o3 = 0.f;
        #pragma unroll
        for (int r = 0; r < 16; ++r) {
            const float4 v = sums[t][r];
            o0 += v.x; o1 += v.y; o2 += v.z; o3 += v.w;
        }

        const float4* xg4 = reinterpret_cast<const float4*>(xg);
        const float4* sw4 = reinterpret_cast<const float4*>(sw);
        const float4* sb4 = reinterpret_cast<const float4*>(sb);
        #pragma unroll 4
        for (int i = 0; i < II; ++i) {
            const float4 xvv = xg4[b * II + i];
            const float4 swv = sw4[i * OO + o];
            const float4 sbv = sb4[i * OO + o];
            const float s0 = xvv.x / (1.f + __expf(-xvv.x));
            const float s1 = xvv.y / (1.f + __expf(-xvv.y));
            const float s2 = xvv.z / (1.f + __expf(-xvv.z));
            const float s3 = xvv.w / (1.f + __expf(-xvv.w));
            o0 += swv.x * s0 + swv.y * s1 + swv.z * s2 - swv.w * s3 + sbv.x;
            o1 += swv.x * s1 + swv.y * s0 - swv.z * s3 + swv.w * s2 + sbv.y;
            o2 += swv.x * s2 + swv.y * s3 + swv.z * s0 - swv.w * s1 + sbv.z;
            o3 += swv.x * s3 + swv.y * s2 - swv.z * s1 + swv.w * s0 + sbv.w;
        }
        reinterpret_cast<float4*>(out)[pg] = make_float4(o0, o1, o2, o3);
    }
}

// ---------------------------------------------------------------------------
// Fallback-only final kernel (atomic path): main sums already in out
// ---------------------------------------------------------------------------
__global__ void kan_out(const float* __restrict__ xg,
                        const float* __restrict__ sw,
                        const float* __restrict__ sb,
                        float* __restrict__ out)
{
    const int t = blockIdx.x * 256 + threadIdx.x;    // (b,o)
    const int b = t >> 6, o = t & 63;

    const float4 v = reinterpret_cast<const float4*>(out)[t];
    float o0 = v.x, o1 = v.y, o2 = v.z, o3 = v.w;

    const float4* xg4 = reinterpret_cast<const float4*>(xg);
    const float4* sw4 = reinterpret_cast<const float4*>(sw);
    const float4* sb4 = reinterpret_cast<const float4*>(sb);
    #pragma unroll 4
    for (int i = 0; i < II; ++i) {
        const float4 xvv = xg4[b * II + i];
        const float4 swv = sw4[i * OO + o];
        const float4 sbv = sb4[i * OO + o];
        const float s0 = xvv.x / (1.f + __expf(-xvv.x));
        const float s1 = xvv.y / (1.f + __expf(-xvv.y));
        const float s2 = xvv.z / (1.f + __expf(-xvv.z));
        const float s3 = xvv.w / (1.f + __expf(-xvv.w));
        o0 += swv.x * s0 + swv.y * s1 + swv.z * s2 - swv.w * s3 + sbv.x;
        o1 += swv.x * s1 + swv.y * s0 - swv.z * s3 + swv.w * s2 + sbv.y;
        o2 += swv.x * s2 + swv.y * s3 + swv.z * s0 - swv.w * s1 + sbv.z;
        o3 += swv.x * s3 + swv.y * s2 - swv.z * s1 + swv.w * s0 + sbv.w;
    }
    reinterpret_cast<float4*>(out)[t] = make_float4(o0, o1, o2, o3);
}

// ---------------------------------------------------------------------------
extern "C" void kernel_launch(void* const* d_in, const int* in_sizes, int n_in,
                              void* d_out, int out_size, void* d_ws, size_t ws_size,
                              hipStream_t stream)
{
    const float* x   = (const float*)d_in[0];
    const float* grd = (const float*)d_in[1];
    const float* w   = (const float*)d_in[2];
    const float* sw  = (const float*)d_in[3];
    const float* sb  = (const float*)d_in[4];
    float* out = (float*)d_out;
    float* ws  = (float*)d_ws;

    const size_t need = (size_t)64 * NCH * 16384 * 4;   // 512 partial slices

    if (ws_size >= need) {
        kan_main<<<dim3(64, NCH), 512, 0, stream>>>(x, grd, w, ws, 0);
        kan_tail<<<256, 256, 0, stream>>>(ws, x, sw, sb, out);
    } else {
        hipMemsetAsync(d_out, 0, (size_t)out_size * sizeof(float), stream);
        kan_main<<<dim3(64, NCH), 512, 0, stream>>>(x, grd, w, out, 1);
        kan_out<<<16, 256, 0, stream>>>(x, sw, sb, out);
    }
}